// Round 1
// baseline (293.516 us; speedup 1.0000x reference)
//
#include <hip/hip_runtime.h>
#include <cstddef>

// Problem constants (from reference): T=2048, B=8, C=1024, H=16, K=31, P=15
constexpr int T_ = 2048;
constexpr int B_ = 8;
constexpr int C_ = 1024;
constexpr int H_ = 16;
constexpr int K_ = 31;
constexpr int P_ = 15;
constexpr int R_ = C_ / H_;       // 64
constexpr int M_ = T_ * B_;       // 16384  (GEMM M)
constexpr int N_ = H_ * K_;       // 496    (GEMM N)

// ---------------------------------------------------------------------------
// Kernel A: logits[m][o] = sum_c X[m][c] * W[o][c]
// fp32 tiled GEMM. BM=128, BN=64, BK=32, 256 threads, 8x4 microtile.
// Both tiles staged transposed [k][m]/[k][n] so inner loop is ds_read_b128s
// + v_fmac_f32. Padding keeps 16B alignment (132, 68 are multiples of 4).
// ---------------------------------------------------------------------------
__global__ __launch_bounds__(256)
void gemm_logits(const float* __restrict__ X, const float* __restrict__ W,
                 float* __restrict__ L) {
    __shared__ float As[32][132];   // [k][m] padded: bank stride 4
    __shared__ float Bs[32][68];    // [k][n] padded

    const int tid = threadIdx.x;
    const int m0 = blockIdx.x * 128;
    const int n0 = blockIdx.y * 64;
    const int tx = tid & 15;        // n direction (4 cols each)
    const int ty = tid >> 4;        // m direction (8 rows each)
    const int lr = tid >> 3;        // loader row 0..31
    const int lc = (tid & 7) * 4;   // loader k-offset 0..28

    float acc[8][4];
#pragma unroll
    for (int i = 0; i < 8; ++i)
#pragma unroll
        for (int j = 0; j < 4; ++j) acc[i][j] = 0.f;

    for (int k0 = 0; k0 < C_; k0 += 32) {
        // ---- stage A tile: 128 rows x 32 k (transposed store) ----
#pragma unroll
        for (int p = 0; p < 4; ++p) {
            const int row = lr + p * 32;
            const float4 a =
                *(const float4*)(X + (size_t)(m0 + row) * C_ + (k0 + lc));
            As[lc + 0][row] = a.x;
            As[lc + 1][row] = a.y;
            As[lc + 2][row] = a.z;
            As[lc + 3][row] = a.w;
        }
        // ---- stage B tile: 64 rows (o-dim of W) x 32 k ----
#pragma unroll
        for (int p = 0; p < 2; ++p) {
            const int row = lr + p * 32;
            float4 bv = make_float4(0.f, 0.f, 0.f, 0.f);
            if (n0 + row < N_)
                bv = *(const float4*)(W + (size_t)(n0 + row) * C_ + (k0 + lc));
            Bs[lc + 0][row] = bv.x;
            Bs[lc + 1][row] = bv.y;
            Bs[lc + 2][row] = bv.z;
            Bs[lc + 3][row] = bv.w;
        }
        __syncthreads();
#pragma unroll
        for (int kk = 0; kk < 32; ++kk) {
            float a[8], b[4];
            *(float4*)&a[0] = *(const float4*)&As[kk][ty * 8];
            *(float4*)&a[4] = *(const float4*)&As[kk][ty * 8 + 4];
            *(float4*)&b[0] = *(const float4*)&Bs[kk][tx * 4];
#pragma unroll
            for (int i = 0; i < 8; ++i)
#pragma unroll
                for (int j = 0; j < 4; ++j)
                    acc[i][j] = fmaf(a[i], b[j], acc[i][j]);
        }
        __syncthreads();
    }

    // ---- store: vector float4 per micro-row; last N-tile fully guarded ----
    const int n = n0 + tx * 4;
    if (n < N_) {                   // N_%4==0 so n<N_ implies n+3<N_
#pragma unroll
        for (int i = 0; i < 8; ++i) {
            const int m = m0 + ty * 8 + i;
            float4 v = make_float4(acc[i][0], acc[i][1], acc[i][2], acc[i][3]);
            *(float4*)(L + (size_t)m * N_ + n) = v;
        }
    }
}

// ---------------------------------------------------------------------------
// Kernel B: fused softmax (over K=31) + depthwise dynamic conv.
// One block = 32 t-rows of one (b,h). x window (62x64 f32) staged in LDS
// (stride 64 -> 2 lanes/bank = free). 32 lanes do the softmax in registers.
// ---------------------------------------------------------------------------
__global__ __launch_bounds__(256)
void softmax_conv(const float* __restrict__ X, const float* __restrict__ L,
                  float* __restrict__ out) {
    __shared__ float xs[62][64];    // rows t0-15 .. t0+46
    __shared__ float wls[32][32];   // softmaxed weights, padded to 32

    const int tid = threadIdx.x;
    const int t0 = blockIdx.x * 32;
    const int bh = (int)blockIdx.y;
    const int b = bh >> 4;          // / H_
    const int h = bh & 15;

    // stage x window: 62 rows x 64 f32, float4 loads
    for (int i4 = tid; i4 < 62 * 16; i4 += 256) {
        const int row = i4 >> 4;
        const int c4 = (i4 & 15) * 4;
        const int t = t0 - P_ + row;
        float4 v = make_float4(0.f, 0.f, 0.f, 0.f);
        if (t >= 0 && t < T_)
            v = *(const float4*)(X + ((size_t)t * B_ + b) * C_ + h * R_ + c4);
        *(float4*)&xs[row][c4] = v;
    }

    // softmax over K=31 for each of the 32 t's (one lane per t)
    if (tid < 32) {
        const int t = t0 + tid;
        const float* lp = L + ((size_t)t * B_ + b) * N_ + h * K_;
        float v[31];
        float mx = -1e30f;
#pragma unroll
        for (int k = 0; k < 31; ++k) {
            v[k] = lp[k];
            mx = fmaxf(mx, v[k]);
        }
        float s = 0.f;
#pragma unroll
        for (int k = 0; k < 31; ++k) {
            v[k] = __expf(v[k] - mx);
            s += v[k];
        }
        const float inv = 1.f / s;
#pragma unroll
        for (int k = 0; k < 31; ++k) wls[tid][k] = v[k] * inv;
    }
    __syncthreads();

    // conv: out[t0+tt, b, h*64+r] = sum_k w[tt][k] * xs[tt+k][r]
    const int r = tid & 63;
    const int ts = tid >> 6;
    for (int tt = ts; tt < 32; tt += 4) {
        float acc = 0.f;
#pragma unroll
        for (int k = 0; k < 31; ++k)
            acc = fmaf(wls[tt][k], xs[tt + k][r], acc);
        out[((size_t)(t0 + tt) * B_ + b) * C_ + h * R_ + r] = acc;
    }
}

// ---------------------------------------------------------------------------
extern "C" void kernel_launch(void* const* d_in, const int* in_sizes, int n_in,
                              void* d_out, int out_size, void* d_ws,
                              size_t ws_size, hipStream_t stream) {
    const float* X = (const float*)d_in[0];   // (T,B,C) fp32
    const float* W = (const float*)d_in[1];   // (H*K, C) fp32
    float* out = (float*)d_out;               // (T,B,C) fp32
    float* L = (float*)d_ws;                  // logits (M_, N_) = 32.5 MB

    // GEMM: grid (M/128, ceil(N/64)=8)
    gemm_logits<<<dim3(M_ / 128, 8), 256, 0, stream>>>(X, W, L);
    // softmax+conv: grid (T/32, B*H)
    softmax_conv<<<dim3(T_ / 32, B_ * H_), 256, 0, stream>>>(X, L, out);
}

// Round 2
// 152.894 us; speedup vs baseline: 1.9197x; 1.9197x over previous
//
#include <hip/hip_runtime.h>
#include <cstddef>
#include <cstdint>

// Problem constants: T=2048, B=8, C=1024, H=16, K=31, P=15
constexpr int T_ = 2048;
constexpr int B_ = 8;
constexpr int C_ = 1024;
constexpr int H_ = 16;
constexpr int K_ = 31;
constexpr int P_ = 15;
constexpr int R_ = C_ / H_;       // 64
constexpr int M_ = T_ * B_;       // 16384
constexpr int N_ = H_ * K_;       // 496
constexpr int LDK = 40;           // padded k-stride (ushorts): 80 B = 5*16 B

typedef short bf16x8 __attribute__((ext_vector_type(8)));
typedef float f32x4 __attribute__((ext_vector_type(4)));

// truncation hi/lo split: x ~= hi + lo with ~2^-16 relative residual
__device__ __forceinline__ void cvt_hilo(float x, unsigned short& hi,
                                         unsigned short& lo) {
    union { float f; uint32_t u; } a;
    a.f = x;
    hi = (unsigned short)(a.u >> 16);
    union { uint32_t u; float f; } b;
    b.u = a.u & 0xffff0000u;
    union { float f; uint32_t u; } c;
    c.f = x - b.f;
    lo = (unsigned short)(c.u >> 16);
}

// ---------------------------------------------------------------------------
// Kernel A: logits[m][o] = sum_c X[m][c]*W[o][c], split-bf16 MFMA.
// BM=BN=128, BK=32, 256 thr (4 waves, 2x2), wave tile 64x64 (16 frags).
// 3 MFMA per frag per k-step (hi*hi + lo*hi + hi*lo), fp32 accumulate.
// ---------------------------------------------------------------------------
__global__ __launch_bounds__(256)
void gemm_logits_mfma(const float* __restrict__ X, const float* __restrict__ W,
                      float* __restrict__ L) {
    __shared__ unsigned short Ah[128][LDK];
    __shared__ unsigned short Al[128][LDK];
    __shared__ unsigned short Bh[128][LDK];
    __shared__ unsigned short Bl[128][LDK];

    const int tid = threadIdx.x;
    const int m0 = blockIdx.x * 128;
    const int n0 = blockIdx.y * 128;
    const int lane = tid & 63;
    const int w = tid >> 6;
    const int wm = (w >> 1) * 64;   // wave row offset in tile
    const int wn = (w & 1) * 64;    // wave col offset in tile
    const int col = lane & 15;
    const int k8 = (lane >> 4) * 8; // k-offset of this lane's fragment
    const int ra = tid >> 3;        // loader row 0..31
    const int k4 = (tid & 7) * 4;   // loader k 0..28

    f32x4 acc[4][4] = {};

    for (int k0 = 0; k0 < C_; k0 += 32) {
        // ---- stage A tile (128x32 f32 -> bf16 hi/lo) ----
#pragma unroll
        for (int p = 0; p < 4; ++p) {
            const int row = ra + p * 32;
            const float4 v =
                *(const float4*)(X + (size_t)(m0 + row) * C_ + k0 + k4);
            ushort4 h, l;
            cvt_hilo(v.x, h.x, l.x);
            cvt_hilo(v.y, h.y, l.y);
            cvt_hilo(v.z, h.z, l.z);
            cvt_hilo(v.w, h.w, l.w);
            *(ushort4*)&Ah[row][k4] = h;
            *(ushort4*)&Al[row][k4] = l;
        }
        // ---- stage B tile (128x32 of W, guarded past N=496) ----
#pragma unroll
        for (int p = 0; p < 4; ++p) {
            const int row = ra + p * 32;
            float4 v = make_float4(0.f, 0.f, 0.f, 0.f);
            if (n0 + row < N_)
                v = *(const float4*)(W + (size_t)(n0 + row) * C_ + k0 + k4);
            ushort4 h, l;
            cvt_hilo(v.x, h.x, l.x);
            cvt_hilo(v.y, h.y, l.y);
            cvt_hilo(v.z, h.z, l.z);
            cvt_hilo(v.w, h.w, l.w);
            *(ushort4*)&Bh[row][k4] = h;
            *(ushort4*)&Bl[row][k4] = l;
        }
        __syncthreads();

        // ---- fragments + MFMA ----
        bf16x8 ah[4], al[4];
#pragma unroll
        for (int mf = 0; mf < 4; ++mf) {
            ah[mf] = *(const bf16x8*)&Ah[wm + mf * 16 + col][k8];
            al[mf] = *(const bf16x8*)&Al[wm + mf * 16 + col][k8];
        }
#pragma unroll
        for (int nf = 0; nf < 4; ++nf) {
            const bf16x8 bh = *(const bf16x8*)&Bh[wn + nf * 16 + col][k8];
            const bf16x8 bl = *(const bf16x8*)&Bl[wn + nf * 16 + col][k8];
#pragma unroll
            for (int mf = 0; mf < 4; ++mf) {
                acc[mf][nf] = __builtin_amdgcn_mfma_f32_16x16x32_bf16(
                    ah[mf], bh, acc[mf][nf], 0, 0, 0);
                acc[mf][nf] = __builtin_amdgcn_mfma_f32_16x16x32_bf16(
                    al[mf], bh, acc[mf][nf], 0, 0, 0);
                acc[mf][nf] = __builtin_amdgcn_mfma_f32_16x16x32_bf16(
                    ah[mf], bl, acc[mf][nf], 0, 0, 0);
            }
        }
        __syncthreads();
    }

    // ---- epilogue: C/D map col=lane&15, row=(lane>>4)*4+reg ----
    const int rbase = (lane >> 4) * 4;
#pragma unroll
    for (int nf = 0; nf < 4; ++nf) {
        const int n = n0 + wn + nf * 16 + col;
        if (n < N_) {
#pragma unroll
            for (int mf = 0; mf < 4; ++mf) {
                const int m = m0 + wm + mf * 16 + rbase;
#pragma unroll
                for (int r = 0; r < 4; ++r)
                    L[(size_t)(m + r) * N_ + n] = acc[mf][nf][r];
            }
        }
    }
}

// ---------------------------------------------------------------------------
// Kernel B: fused softmax (K=31) + depthwise dynamic conv (unchanged).
// ---------------------------------------------------------------------------
__global__ __launch_bounds__(256)
void softmax_conv(const float* __restrict__ X, const float* __restrict__ L,
                  float* __restrict__ out) {
    __shared__ float xs[62][64];
    __shared__ float wls[32][32];

    const int tid = threadIdx.x;
    const int t0 = blockIdx.x * 32;
    const int bh = (int)blockIdx.y;
    const int b = bh >> 4;
    const int h = bh & 15;

    for (int i4 = tid; i4 < 62 * 16; i4 += 256) {
        const int row = i4 >> 4;
        const int c4 = (i4 & 15) * 4;
        const int t = t0 - P_ + row;
        float4 v = make_float4(0.f, 0.f, 0.f, 0.f);
        if (t >= 0 && t < T_)
            v = *(const float4*)(X + ((size_t)t * B_ + b) * C_ + h * R_ + c4);
        *(float4*)&xs[row][c4] = v;
    }

    if (tid < 32) {
        const int t = t0 + tid;
        const float* lp = L + ((size_t)t * B_ + b) * N_ + h * K_;
        float v[31];
        float mx = -1e30f;
#pragma unroll
        for (int k = 0; k < 31; ++k) {
            v[k] = lp[k];
            mx = fmaxf(mx, v[k]);
        }
        float s = 0.f;
#pragma unroll
        for (int k = 0; k < 31; ++k) {
            v[k] = __expf(v[k] - mx);
            s += v[k];
        }
        const float inv = 1.f / s;
#pragma unroll
        for (int k = 0; k < 31; ++k) wls[tid][k] = v[k] * inv;
    }
    __syncthreads();

    const int r = tid & 63;
    const int ts = tid >> 6;
    for (int tt = ts; tt < 32; tt += 4) {
        float acc = 0.f;
#pragma unroll
        for (int k = 0; k < 31; ++k)
            acc = fmaf(wls[tt][k], xs[tt + k][r], acc);
        out[((size_t)(t0 + tt) * B_ + b) * C_ + h * R_ + r] = acc;
    }
}

// ---------------------------------------------------------------------------
extern "C" void kernel_launch(void* const* d_in, const int* in_sizes, int n_in,
                              void* d_out, int out_size, void* d_ws,
                              size_t ws_size, hipStream_t stream) {
    const float* X = (const float*)d_in[0];
    const float* W = (const float*)d_in[1];
    float* out = (float*)d_out;
    float* L = (float*)d_ws;   // logits (M_, N_) = 32.5 MB

    gemm_logits_mfma<<<dim3(M_ / 128, (N_ + 127) / 128), 256, 0, stream>>>(X, W, L);
    softmax_conv<<<dim3(T_ / 32, B_ * H_), 256, 0, stream>>>(X, L, out);
}

// Round 3
// 107.996 us; speedup vs baseline: 2.7178x; 1.4157x over previous
//
#include <hip/hip_runtime.h>
#include <cstddef>
#include <cstdint>

// Problem constants: T=2048, B=8, C=1024, H=16, K=31, P=15
constexpr int T_ = 2048;
constexpr int B_ = 8;
constexpr int C_ = 1024;
constexpr int H_ = 16;
constexpr int K_ = 31;
constexpr int P_ = 15;
constexpr int R_ = C_ / H_;       // 64
constexpr int M_ = T_ * B_;       // 16384
constexpr int N_ = H_ * K_;       // 496
constexpr int NPAD = 512;         // W padded rows

typedef _Float16 f16x8 __attribute__((ext_vector_type(8)));
typedef _Float16 f16x4 __attribute__((ext_vector_type(4)));
typedef short bf16x8 __attribute__((ext_vector_type(8)));
typedef float f32x4 __attribute__((ext_vector_type(4)));

// async 16B global->LDS copy (wave-uniform base + lane*16 semantics)
__device__ __forceinline__ void async_cp16(const void* g, void* l) {
    __builtin_amdgcn_global_load_lds(
        (const __attribute__((address_space(1))) void*)g,
        (__attribute__((address_space(3))) void*)l, 16, 0, 0);
}

// ---------------------------------------------------------------------------
// Kernel 0: convert X -> fp16 (Xh), W -> fp16 padded to 512 rows (Wh)
// ---------------------------------------------------------------------------
constexpr int XVEC = T_ * B_ * C_ / 4;        // 4,194,304 float4
constexpr int WVEC = NPAD * C_ / 4;           // 131,072 target half4
constexpr int WSRC = N_ * C_ / 4;             // 126,976 valid source float4

__global__ __launch_bounds__(256)
void cvt_half(const float4* __restrict__ Xv, const float4* __restrict__ Wv,
              f16x4* __restrict__ Xh, f16x4* __restrict__ Wh) {
    const int i = blockIdx.x * 256 + threadIdx.x;
    if (i < XVEC) {
        const float4 v = Xv[i];
        f16x4 h;
        h[0] = (_Float16)v.x; h[1] = (_Float16)v.y;
        h[2] = (_Float16)v.z; h[3] = (_Float16)v.w;
        Xh[i] = h;
    } else {
        const int j = i - XVEC;
        float4 v = make_float4(0.f, 0.f, 0.f, 0.f);
        if (j < WSRC) v = Wv[j];
        f16x4 h;
        h[0] = (_Float16)v.x; h[1] = (_Float16)v.y;
        h[2] = (_Float16)v.z; h[3] = (_Float16)v.w;
        Wh[j] = h;
    }
}

// ---------------------------------------------------------------------------
// Kernel A: logits = Xh * Wh^T, fp16 MFMA, m97 structure.
// BM=BN=128, BK=32, 256 thr (4 waves 2x2), wave tile 64x64 (4x4 frags).
// Linear LDS (global_load_lds requires it), 2 barriers per k-step.
// ---------------------------------------------------------------------------
__global__ __launch_bounds__(256)
void gemm_f16(const _Float16* __restrict__ Xh, const _Float16* __restrict__ Wh,
              float* __restrict__ L) {
    __shared__ _Float16 As[128 * 32];
    __shared__ _Float16 Bs[128 * 32];

    const int tid = threadIdx.x;
    const int m0 = blockIdx.x * 128;
    const int n0 = blockIdx.y * 128;
    const int lane = tid & 63;
    const int w = tid >> 6;
    const int wm = (w >> 1) * 64;
    const int wn = (w & 1) * 64;
    const int col = lane & 15;
    const int k8 = (lane >> 4) * 8;

    // staging map: thread -> (row = tid>>2, 16B chunk = (tid&3)*8 halves)
    const int srow = tid >> 2;
    const int scol = (tid & 3) * 8;
    const _Float16* ga0 = Xh + (size_t)(m0 + srow) * C_ + scol;
    const _Float16* ga1 = ga0 + (size_t)64 * C_;
    const _Float16* gb0 = Wh + (size_t)(n0 + srow) * C_ + scol;
    const _Float16* gb1 = gb0 + (size_t)64 * C_;

    f32x4 acc[4][4] = {};

    for (int k0 = 0; k0 < C_; k0 += 32) {
        async_cp16(ga0 + k0, &As[tid * 8]);
        async_cp16(ga1 + k0, &As[2048 + tid * 8]);
        async_cp16(gb0 + k0, &Bs[tid * 8]);
        async_cp16(gb1 + k0, &Bs[2048 + tid * 8]);
        __syncthreads();   // drains vmcnt before ds_read

        f16x8 a[4], b[4];
#pragma unroll
        for (int mf = 0; mf < 4; ++mf)
            a[mf] = *(const f16x8*)&As[(wm + mf * 16 + col) * 32 + k8];
#pragma unroll
        for (int nf = 0; nf < 4; ++nf)
            b[nf] = *(const f16x8*)&Bs[(wn + nf * 16 + col) * 32 + k8];
#pragma unroll
        for (int nf = 0; nf < 4; ++nf)
#pragma unroll
            for (int mf = 0; mf < 4; ++mf)
                acc[mf][nf] = __builtin_amdgcn_mfma_f32_16x16x32_f16(
                    a[mf], b[nf], acc[mf][nf], 0, 0, 0);
        __syncthreads();
    }

    // epilogue: C/D map col=lane&15, row=(lane>>4)*4+reg
    const int rb = (lane >> 4) * 4;
#pragma unroll
    for (int nf = 0; nf < 4; ++nf) {
        const int n = n0 + wn + nf * 16 + col;
        if (n < N_) {
#pragma unroll
            for (int mf = 0; mf < 4; ++mf) {
                const int m = m0 + wm + mf * 16 + rb;
#pragma unroll
                for (int r = 0; r < 4; ++r)
                    L[(size_t)(m + r) * N_ + n] = acc[mf][nf][r];
            }
        }
    }
}

// ---------------------------------------------------------------------------
// Kernel B: fused softmax (K=31) + depthwise dynamic conv; x read as fp16.
// ---------------------------------------------------------------------------
__global__ __launch_bounds__(256)
void softmax_conv_h(const _Float16* __restrict__ Xh, const float* __restrict__ L,
                    float* __restrict__ out) {
    __shared__ float xs[62][64];
    __shared__ float wls[32][32];

    const int tid = threadIdx.x;
    const int t0 = blockIdx.x * 32;
    const int bh = (int)blockIdx.y;
    const int b = bh >> 4;
    const int h = bh & 15;

    // stage x window: 62 rows x 64 halves, 16B chunks, convert to f32 in LDS
    for (int i = tid; i < 62 * 8; i += 256) {
        const int row = i >> 3;
        const int c8 = (i & 7) * 8;
        const int t = t0 - P_ + row;
        f16x8 v = {};
        if (t >= 0 && t < T_)
            v = *(const f16x8*)(Xh + ((size_t)t * B_ + b) * C_ + h * R_ + c8);
#pragma unroll
        for (int j = 0; j < 8; ++j) xs[row][c8 + j] = (float)v[j];
    }

    if (tid < 32) {
        const int t = t0 + tid;
        const float* lp = L + ((size_t)t * B_ + b) * N_ + h * K_;
        float v[31];
        float mx = -1e30f;
#pragma unroll
        for (int k = 0; k < 31; ++k) {
            v[k] = lp[k];
            mx = fmaxf(mx, v[k]);
        }
        float s = 0.f;
#pragma unroll
        for (int k = 0; k < 31; ++k) {
            v[k] = __expf(v[k] - mx);
            s += v[k];
        }
        const float inv = 1.f / s;
#pragma unroll
        for (int k = 0; k < 31; ++k) wls[tid][k] = v[k] * inv;
    }
    __syncthreads();

    const int r = tid & 63;
    const int ts = tid >> 6;
    for (int tt = ts; tt < 32; tt += 4) {
        float acc = 0.f;
#pragma unroll
        for (int k = 0; k < 31; ++k)
            acc = fmaf(wls[tt][k], xs[tt + k][r], acc);
        out[((size_t)(t0 + tt) * B_ + b) * C_ + h * R_ + r] = acc;
    }
}

// ===========================================================================
// Fallback path (round-2): used only if ws_size < 64 MiB.
// ===========================================================================
constexpr int LDK = 40;

__device__ __forceinline__ void cvt_hilo(float x, unsigned short& hi,
                                         unsigned short& lo) {
    union { float f; uint32_t u; } a; a.f = x;
    hi = (unsigned short)(a.u >> 16);
    union { uint32_t u; float f; } bb; bb.u = a.u & 0xffff0000u;
    union { float f; uint32_t u; } c; c.f = x - bb.f;
    lo = (unsigned short)(c.u >> 16);
}

__global__ __launch_bounds__(256)
void gemm_logits_mfma(const float* __restrict__ X, const float* __restrict__ W,
                      float* __restrict__ L) {
    __shared__ unsigned short Ah[128][LDK];
    __shared__ unsigned short Al[128][LDK];
    __shared__ unsigned short Bh[128][LDK];
    __shared__ unsigned short Bl[128][LDK];

    const int tid = threadIdx.x;
    const int m0 = blockIdx.x * 128;
    const int n0 = blockIdx.y * 128;
    const int lane = tid & 63;
    const int w = tid >> 6;
    const int wm = (w >> 1) * 64;
    const int wn = (w & 1) * 64;
    const int col = lane & 15;
    const int k8 = (lane >> 4) * 8;
    const int ra = tid >> 3;
    const int k4 = (tid & 7) * 4;

    f32x4 acc[4][4] = {};

    for (int k0 = 0; k0 < C_; k0 += 32) {
#pragma unroll
        for (int p = 0; p < 4; ++p) {
            const int row = ra + p * 32;
            const float4 v = *(const float4*)(X + (size_t)(m0 + row) * C_ + k0 + k4);
            ushort4 h, l;
            cvt_hilo(v.x, h.x, l.x); cvt_hilo(v.y, h.y, l.y);
            cvt_hilo(v.z, h.z, l.z); cvt_hilo(v.w, h.w, l.w);
            *(ushort4*)&Ah[row][k4] = h;
            *(ushort4*)&Al[row][k4] = l;
        }
#pragma unroll
        for (int p = 0; p < 4; ++p) {
            const int row = ra + p * 32;
            float4 v = make_float4(0.f, 0.f, 0.f, 0.f);
            if (n0 + row < N_)
                v = *(const float4*)(W + (size_t)(n0 + row) * C_ + k0 + k4);
            ushort4 h, l;
            cvt_hilo(v.x, h.x, l.x); cvt_hilo(v.y, h.y, l.y);
            cvt_hilo(v.z, h.z, l.z); cvt_hilo(v.w, h.w, l.w);
            *(ushort4*)&Bh[row][k4] = h;
            *(ushort4*)&Bl[row][k4] = l;
        }
        __syncthreads();
        bf16x8 ah[4], al[4];
#pragma unroll
        for (int mf = 0; mf < 4; ++mf) {
            ah[mf] = *(const bf16x8*)&Ah[wm + mf * 16 + col][k8];
            al[mf] = *(const bf16x8*)&Al[wm + mf * 16 + col][k8];
        }
#pragma unroll
        for (int nf = 0; nf < 4; ++nf) {
            const bf16x8 bh = *(const bf16x8*)&Bh[wn + nf * 16 + col][k8];
            const bf16x8 bl = *(const bf16x8*)&Bl[wn + nf * 16 + col][k8];
#pragma unroll
            for (int mf = 0; mf < 4; ++mf) {
                acc[mf][nf] = __builtin_amdgcn_mfma_f32_16x16x32_bf16(ah[mf], bh, acc[mf][nf], 0, 0, 0);
                acc[mf][nf] = __builtin_amdgcn_mfma_f32_16x16x32_bf16(al[mf], bh, acc[mf][nf], 0, 0, 0);
                acc[mf][nf] = __builtin_amdgcn_mfma_f32_16x16x32_bf16(ah[mf], bl, acc[mf][nf], 0, 0, 0);
            }
        }
        __syncthreads();
    }
    const int rb = (lane >> 4) * 4;
#pragma unroll
    for (int nf = 0; nf < 4; ++nf) {
        const int n = n0 + wn + nf * 16 + col;
        if (n < N_) {
#pragma unroll
            for (int mf = 0; mf < 4; ++mf) {
                const int m = m0 + wm + mf * 16 + rb;
#pragma unroll
                for (int r = 0; r < 4; ++r)
                    L[(size_t)(m + r) * N_ + n] = acc[mf][nf][r];
            }
        }
    }
}

__global__ __launch_bounds__(256)
void softmax_conv_f32(const float* __restrict__ X, const float* __restrict__ L,
                      float* __restrict__ out) {
    __shared__ float xs[62][64];
    __shared__ float wls[32][32];
    const int tid = threadIdx.x;
    const int t0 = blockIdx.x * 32;
    const int bh = (int)blockIdx.y;
    const int b = bh >> 4;
    const int h = bh & 15;
    for (int i4 = tid; i4 < 62 * 16; i4 += 256) {
        const int row = i4 >> 4;
        const int c4 = (i4 & 15) * 4;
        const int t = t0 - P_ + row;
        float4 v = make_float4(0.f, 0.f, 0.f, 0.f);
        if (t >= 0 && t < T_)
            v = *(const float4*)(X + ((size_t)t * B_ + b) * C_ + h * R_ + c4);
        *(float4*)&xs[row][c4] = v;
    }
    if (tid < 32) {
        const int t = t0 + tid;
        const float* lp = L + ((size_t)t * B_ + b) * N_ + h * K_;
        float v[31];
        float mx = -1e30f;
#pragma unroll
        for (int k = 0; k < 31; ++k) { v[k] = lp[k]; mx = fmaxf(mx, v[k]); }
        float s = 0.f;
#pragma unroll
        for (int k = 0; k < 31; ++k) { v[k] = __expf(v[k] - mx); s += v[k]; }
        const float inv = 1.f / s;
#pragma unroll
        for (int k = 0; k < 31; ++k) wls[tid][k] = v[k] * inv;
    }
    __syncthreads();
    const int r = tid & 63;
    const int ts = tid >> 6;
    for (int tt = ts; tt < 32; tt += 4) {
        float acc = 0.f;
#pragma unroll
        for (int k = 0; k < 31; ++k)
            acc = fmaf(wls[tt][k], xs[tt + k][r], acc);
        out[((size_t)(t0 + tt) * B_ + b) * C_ + h * R_ + r] = acc;
    }
}

// ---------------------------------------------------------------------------
extern "C" void kernel_launch(void* const* d_in, const int* in_sizes, int n_in,
                              void* d_out, int out_size, void* d_ws,
                              size_t ws_size, hipStream_t stream) {
    const float* X = (const float*)d_in[0];
    const float* W = (const float*)d_in[1];
    float* out = (float*)d_out;

    const size_t L_bytes = (size_t)M_ * N_ * 4;          // 32,505,856
    const size_t Xh_bytes = (size_t)M_ * C_ * 2;         // 33,554,432
    const size_t Wh_bytes = (size_t)NPAD * C_ * 2;       //  1,048,576
    const size_t need = L_bytes + Xh_bytes + Wh_bytes;   // 64 MiB

    float* L = (float*)d_ws;

    if (ws_size >= need) {
        _Float16* Xh = (_Float16*)((char*)d_ws + L_bytes);
        _Float16* Wh = (_Float16*)((char*)d_ws + L_bytes + Xh_bytes);

        cvt_half<<<(XVEC + WVEC) / 256, 256, 0, stream>>>(
            (const float4*)X, (const float4*)W, (f16x4*)Xh, (f16x4*)Wh);
        gemm_f16<<<dim3(M_ / 128, NPAD / 128), 256, 0, stream>>>(Xh, Wh, L);
        softmax_conv_h<<<dim3(T_ / 32, B_ * H_), 256, 0, stream>>>(Xh, L, out);
    } else {
        gemm_logits_mfma<<<dim3(M_ / 128, (N_ + 127) / 128), 256, 0, stream>>>(X, W, L);
        softmax_conv_f32<<<dim3(T_ / 32, B_ * H_), 256, 0, stream>>>(X, L, out);
    }
}

// Round 5
// 94.872 us; speedup vs baseline: 3.0938x; 1.1383x over previous
//
#include <hip/hip_runtime.h>
#include <cstddef>
#include <cstdint>

// Problem constants: T=2048, B=8, C=1024, H=16, K=31, P=15
constexpr int T_ = 2048;
constexpr int B_ = 8;
constexpr int C_ = 1024;
constexpr int H_ = 16;
constexpr int K_ = 31;
constexpr int P_ = 15;
constexpr int M_ = T_ * B_;   // 16384
constexpr int N_ = H_ * K_;   // 496
constexpr int NP = 512;       // padded N

typedef _Float16 f16x4 __attribute__((ext_vector_type(4)));
typedef _Float16 f16x8 __attribute__((ext_vector_type(8)));
typedef float f32x4 __attribute__((ext_vector_type(4)));

__device__ __forceinline__ void async_cp16(const void* g, void* l) {
    __builtin_amdgcn_global_load_lds(
        (const __attribute__((address_space(1))) void*)g,
        (__attribute__((address_space(3))) void*)l, 16, 0, 0);
}

// ---------------------------------------------------------------------------
// K0: W (496x1024 f32) -> Wh (512x1024 fp16, zero-padded rows), with each
// row's 16B chunks permuted within a 4-chunk (64B) group: position jst holds
// logical chunk (jst ^ (n&3)). K1's linear global_load_lds then lands a
// swizzled Bs whose B-fragment reads are bank-spread.
// ---------------------------------------------------------------------------
__global__ __launch_bounds__(256)
void cvt_w(const float* __restrict__ W, _Float16* __restrict__ Wh) {
    const int cc = blockIdx.x * 256 + threadIdx.x;   // chunk-of-8-halves id
    const int n = cc >> 7;          // row 0..511 (128 chunks per row)
    const int sp = cc & 127;        // store chunk position in row
    const int ksp = sp >> 2;        // 64B group (k-step quarter)
    const int jst = sp & 3;
    const int jl = jst ^ (n & 3);   // logical chunk held at this position
    const int k0 = ksp * 32 + jl * 8;
    f16x8 hv = {};
    if (n < N_) {
        const float4 v0 = *(const float4*)(W + (size_t)n * C_ + k0);
        const float4 v1 = *(const float4*)(W + (size_t)n * C_ + k0 + 4);
        hv[0] = (_Float16)v0.x; hv[1] = (_Float16)v0.y;
        hv[2] = (_Float16)v0.z; hv[3] = (_Float16)v0.w;
        hv[4] = (_Float16)v1.x; hv[5] = (_Float16)v1.y;
        hv[6] = (_Float16)v1.z; hv[7] = (_Float16)v1.w;
    }
    *(f16x8*)&Wh[(size_t)n * C_ + sp * 8] = hv;
}

// ---------------------------------------------------------------------------
// K1: fused GEMM (logits = X*W^T, fp16 MFMA) + softmax -> WSM fp16.
// 256 blocks (BM=64 x full N=512), 512 threads (8 waves, each 64m x 64n).
// A: reg-staged f32->fp16 into padded As[64][40]. B: global_load_lds from
// pre-permuted Wh into linear Bs[512][32]. Logits stay in an LDS overlay.
// ---------------------------------------------------------------------------
__global__ __launch_bounds__(512, 2)
void gemm_softmax(const float* __restrict__ X, const _Float16* __restrict__ Wh,
                  _Float16* __restrict__ WSM) {
    __shared__ union {
        struct { _Float16 As[64 * 40]; _Float16 Bs[NP * 32]; } s;
        _Float16 Ls[64 * 512];   // logits overlay (phase-disjoint)
    } u;

    const int tid = threadIdx.x;
    const int lane = tid & 63;
    const int w = tid >> 6;          // wave 0..7 -> n-range w*64
    const int col = lane & 15;
    const int g = lane >> 4;         // k-chunk group 0..3
    const int k8 = g * 8;
    const int m0 = blockIdx.x * 64;

    const int arow = tid >> 3;          // 0..63
    const int akq = (tid & 7) * 4;      // 0..28
    const float* aptr = X + (size_t)(m0 + arow) * C_ + akq;

    f32x4 acc[4][4] = {};

    for (int k0 = 0; k0 < C_; k0 += 32) {
        // ---- A stage: 64x32 f32 -> fp16 (one float4 per thread) ----
        const float4 av = *(const float4*)(aptr + k0);
        f16x4 a4;
        a4[0] = (_Float16)av.x; a4[1] = (_Float16)av.y;
        a4[2] = (_Float16)av.z; a4[3] = (_Float16)av.w;
        *(f16x4*)&u.s.As[arow * 40 + akq] = a4;
        // ---- B stage: 512x32 via global_load_lds (4 chunks/thread) ----
#pragma unroll
        for (int p = 0; p < 4; ++p) {
            const int ci = p * 512 + tid;          // chunk id 0..2047
            const int n = ci >> 2, jp = ci & 3;    // row, position
            async_cp16(Wh + (size_t)n * C_ + k0 + jp * 8, &u.s.Bs[ci * 8]);
        }
        __syncthreads();

        f16x8 a[4], b[4];
#pragma unroll
        for (int mf = 0; mf < 4; ++mf)
            a[mf] = *(const f16x8*)&u.s.As[(mf * 16 + col) * 40 + k8];
#pragma unroll
        for (int nf = 0; nf < 4; ++nf) {
            const int nl = w * 64 + nf * 16 + col;
            const int jp = g ^ (nl & 3);           // undo baked permutation
            b[nf] = *(const f16x8*)&u.s.Bs[nl * 32 + jp * 8];
        }
#pragma unroll
        for (int nf = 0; nf < 4; ++nf)
#pragma unroll
            for (int mf = 0; mf < 4; ++mf)
                acc[mf][nf] = __builtin_amdgcn_mfma_f32_16x16x32_f16(
                    a[mf], b[nf], acc[mf][nf], 0, 0, 0);
        __syncthreads();
    }

    // ---- epilogue: dump logits to Ls[64][h*32+k] fp16 ----
    const int rb = g * 4;
#pragma unroll
    for (int nf = 0; nf < 4; ++nf) {
        const int nl = w * 64 + nf * 16 + col;
        if (nl < N_) {
            const int h = (nl * 8457) >> 18;       // nl/31 for nl<496
            const int slot = h * 32 + (nl - h * 31);
#pragma unroll
            for (int mf = 0; mf < 4; ++mf) {
                const int mr = mf * 16 + rb;
#pragma unroll
                for (int r = 0; r < 4; ++r)
                    u.Ls[(mr + r) * 512 + slot] = (_Float16)acc[mf][nf][r];
            }
        }
    }
    __syncthreads();

    // ---- softmax: 1024 (t,h) rows, 2 per thread; write WSM fp16 ----
#pragma unroll
    for (int p = 0; p < 2; ++p) {
        const int idx = tid + p * 512;
        const int mr = idx >> 4, h = idx & 15;
        const _Float16* lp = &u.Ls[mr * 512 + h * 32];
        float v[31];
#pragma unroll
        for (int c = 0; c < 4; ++c) {
            const f16x8 ch = *(const f16x8*)(lp + c * 8);
#pragma unroll
            for (int e = 0; e < 8; ++e) {
                const int k = c * 8 + e;
                if (k < 31) v[k] = (float)ch[e];
            }
        }
        float mx = v[0];
#pragma unroll
        for (int k = 1; k < 31; ++k) mx = fmaxf(mx, v[k]);
        float ssum = 0.f;
#pragma unroll
        for (int k = 0; k < 31; ++k) { v[k] = __expf(v[k] - mx); ssum += v[k]; }
        const float inv = 1.f / ssum;
        _Float16* op = WSM + (size_t)(m0 + mr) * 512 + h * 32;
#pragma unroll
        for (int c = 0; c < 4; ++c) {
            f16x8 ov;
#pragma unroll
            for (int e = 0; e < 8; ++e) {
                const int k = c * 8 + e;
                ov[e] = (k < 31) ? (_Float16)(v[k] * inv) : (_Float16)0.f;
            }
            *(f16x8*)(op + c * 8) = ov;
        }
    }
}

// ---------------------------------------------------------------------------
// K2: depthwise dynamic conv. Block = 64 t x one (b,h). xs[94][64] f32 with
// 16B-chunk XOR swizzle (row&7) for bank-free strided reads; ws[64][36] f32.
// Thread = (c-slot s, 4 consecutive t): shared-u loop -> each x b128 read
// feeds up to 16 fmas; w register-cached 4-wide.
// ---------------------------------------------------------------------------
__global__ __launch_bounds__(256)
void dconv(const float* __restrict__ X, const _Float16* __restrict__ WSM,
           float* __restrict__ out) {
    __shared__ float xs[94][64];
    __shared__ float ws[64][36];

    const int tid = threadIdx.x;
    const int t0 = blockIdx.x * 64;
    const int bh = (int)blockIdx.y;
    const int b = bh >> 4, h = bh & 15;

    // stage x window rows t0-15 .. t0+78 (swizzled 16B chunks)
    for (int task = tid; task < 94 * 16; task += 256) {
        const int r = task >> 4, sc = task & 15;
        const int tp = t0 + r - 15;
        f32x4 v = {};
        if (tp >= 0 && tp < T_)
            v = *(const f32x4*)(X + ((size_t)tp * B_ + b) * C_ + h * 64 + sc * 4);
        *(f32x4*)&xs[r][(sc ^ (r & 7)) * 4] = v;
    }
    // stage softmaxed weights (fp16 -> f32)
    {
        const int t = tid >> 2, kc = (tid & 3) * 8;
        const f16x8 wv =
            *(const f16x8*)(WSM + (size_t)((t0 + t) * B_ + b) * 512 + h * 32 + kc);
#pragma unroll
        for (int e = 0; e < 8; ++e) ws[t][kc + e] = (float)wv[e];
    }
    __syncthreads();

    const int s = tid & 15;
    const int tg4 = (tid >> 4) * 4;   // first of this thread's 4 t's
    f32x4 acc[4] = {};
    f32x4 wc[4];

#pragma unroll
    for (int rr = 0; rr < 34; ++rr) {
        const int r = tg4 + rr;
        const f32x4 xv = *(const f32x4*)&xs[r][(s ^ (r & 7)) * 4];
#pragma unroll
        for (int i = 0; i < 4; ++i) {
            const int k = rr - i;
            if (k < 0 || k > 30) continue;
            if ((k & 3) == 0) wc[i] = *(const f32x4*)&ws[tg4 + i][k];
            acc[i] += wc[i][k & 3] * xv;
        }
    }

#pragma unroll
    for (int i = 0; i < 4; ++i) {
        const int t = t0 + tg4 + i;
        *(f32x4*)(out + ((size_t)t * B_ + b) * C_ + h * 64 + s * 4) = acc[i];
    }
}

// ---------------------------------------------------------------------------
extern "C" void kernel_launch(void* const* d_in, const int* in_sizes, int n_in,
                              void* d_out, int out_size, void* d_ws,
                              size_t ws_size, hipStream_t stream) {
    const float* X = (const float*)d_in[0];
    const float* W = (const float*)d_in[1];
    float* out = (float*)d_out;

    _Float16* Wh = (_Float16*)d_ws;                              // 1 MiB
    _Float16* WSM = (_Float16*)((char*)d_ws + (size_t)NP * C_ * 2);  // 16 MiB

    cvt_w<<<256, 256, 0, stream>>>(W, Wh);
    gemm_softmax<<<256, 512, 0, stream>>>(X, Wh, WSM);
    dconv<<<dim3(T_ / 64, B_ * H_), 256, 0, stream>>>(X, WSM, out);
}

// Round 6
// 85.598 us; speedup vs baseline: 3.4290x; 1.1083x over previous
//
#include <hip/hip_runtime.h>
#include <cstddef>
#include <cstdint>

// Problem constants: T=2048, B=8, C=1024, H=16, K=31, P=15
constexpr int T_ = 2048;
constexpr int B_ = 8;
constexpr int C_ = 1024;
constexpr int H_ = 16;
constexpr int K_ = 31;
constexpr int P_ = 15;
constexpr int M_ = T_ * B_;   // 16384
constexpr int N_ = H_ * K_;   // 496
constexpr int NP = 512;       // padded N

typedef _Float16 f16x4 __attribute__((ext_vector_type(4)));
typedef _Float16 f16x8 __attribute__((ext_vector_type(8)));
typedef float f32x4 __attribute__((ext_vector_type(4)));

__device__ __forceinline__ void async_cp16(const void* g, void* l) {
    __builtin_amdgcn_global_load_lds(
        (const __attribute__((address_space(1))) void*)g,
        (__attribute__((address_space(3))) void*)l, 16, 0, 0);
}

// ---------------------------------------------------------------------------
// K0: W (496x1024 f32) -> Wh (512x1024 fp16, zero-padded rows), with each
// row's 16B chunks permuted within a 4-chunk (64B) group: position jst holds
// logical chunk (jst ^ (n&3)). K1's linear global_load_lds then lands a
// swizzled Bs whose B-fragment reads are bank-spread.
// ---------------------------------------------------------------------------
__global__ __launch_bounds__(256)
void cvt_w(const float* __restrict__ W, _Float16* __restrict__ Wh) {
    const int cc = blockIdx.x * 256 + threadIdx.x;   // chunk-of-8-halves id
    const int n = cc >> 7;          // row 0..511 (128 chunks per row)
    const int sp = cc & 127;        // store chunk position in row
    const int ksp = sp >> 2;        // 64B group (k-step quarter)
    const int jst = sp & 3;
    const int jl = jst ^ (n & 3);   // logical chunk held at this position
    const int k0 = ksp * 32 + jl * 8;
    f16x8 hv = {};
    if (n < N_) {
        const float4 v0 = *(const float4*)(W + (size_t)n * C_ + k0);
        const float4 v1 = *(const float4*)(W + (size_t)n * C_ + k0 + 4);
        hv[0] = (_Float16)v0.x; hv[1] = (_Float16)v0.y;
        hv[2] = (_Float16)v0.z; hv[3] = (_Float16)v0.w;
        hv[4] = (_Float16)v1.x; hv[5] = (_Float16)v1.y;
        hv[6] = (_Float16)v1.z; hv[7] = (_Float16)v1.w;
    }
    *(f16x8*)&Wh[(size_t)n * C_ + sp * 8] = hv;
}

// ---------------------------------------------------------------------------
// K1: fused GEMM (logits = X*W^T, fp16 MFMA) + softmax -> WSM fp16.
// 256 blocks (BM=64 x full N=512), 512 threads (8 waves, each 64m x 64n).
// 2-phase software pipeline: double-buffered As/Bs; iteration t issues
// t+1's loads first (A->reg, B->LDS async), computes t, writes A(t+1) to
// LDS after the MFMAs, then one barrier. Logits stay in an LDS overlay.
// ---------------------------------------------------------------------------
__global__ __launch_bounds__(512, 2)
void gemm_softmax(const float* __restrict__ X, const _Float16* __restrict__ Wh,
                  _Float16* __restrict__ WSM) {
    __shared__ union {
        struct { _Float16 As[2][64 * 40]; _Float16 Bs[2][NP * 32]; } s;
        _Float16 Ls[64 * 512];   // logits overlay (phase-disjoint)
    } u;

    const int tid = threadIdx.x;
    const int lane = tid & 63;
    const int w = tid >> 6;          // wave 0..7 -> n-range w*64
    const int col = lane & 15;
    const int g = lane >> 4;         // k-chunk group 0..3
    const int k8 = g * 8;
    const int m0 = blockIdx.x * 64;

    const int arow = tid >> 3;          // 0..63
    const int akq = (tid & 7) * 4;      // 0..28
    const float* aptr = X + (size_t)(m0 + arow) * C_ + akq;

    // B staging: 4 chunks per thread, fixed (n, position) per chunk id
    int bn[4], bj[4];
#pragma unroll
    for (int p = 0; p < 4; ++p) {
        const int ci = p * 512 + tid;
        bn[p] = ci >> 2;
        bj[p] = ci & 3;
    }

    f32x4 acc[4][4] = {};

    // ---- prologue: stage k-step 0 into buffer 0 ----
    {
        const float4 av = *(const float4*)(aptr);
        f16x4 a4;
        a4[0] = (_Float16)av.x; a4[1] = (_Float16)av.y;
        a4[2] = (_Float16)av.z; a4[3] = (_Float16)av.w;
        *(f16x4*)&u.s.As[0][arow * 40 + akq] = a4;
#pragma unroll
        for (int p = 0; p < 4; ++p) {
            const int ci = p * 512 + tid;
            async_cp16(Wh + (size_t)bn[p] * C_ + 0 + bj[p] * 8,
                       &u.s.Bs[0][ci * 8]);
        }
    }
    __syncthreads();

    int cur = 0;
    for (int t = 0; t < 32; ++t) {
        const int k1 = (t + 1) * 32;
        float4 avn;
        if (t < 31) {
            // issue next A load (to regs) and next B loads (to LDS buf^1)
            avn = *(const float4*)(aptr + k1);
#pragma unroll
            for (int p = 0; p < 4; ++p) {
                const int ci = p * 512 + tid;
                async_cp16(Wh + (size_t)bn[p] * C_ + k1 + bj[p] * 8,
                           &u.s.Bs[cur ^ 1][ci * 8]);
            }
        }

        // ---- compute k-step t from buf[cur] ----
        f16x8 a[4], b[4];
#pragma unroll
        for (int mf = 0; mf < 4; ++mf)
            a[mf] = *(const f16x8*)&u.s.As[cur][(mf * 16 + col) * 40 + k8];
#pragma unroll
        for (int nf = 0; nf < 4; ++nf) {
            const int nl = w * 64 + nf * 16 + col;
            const int jp = g ^ (nl & 3);           // undo baked permutation
            b[nf] = *(const f16x8*)&u.s.Bs[cur][nl * 32 + jp * 8];
        }
#pragma unroll
        for (int nf = 0; nf < 4; ++nf)
#pragma unroll
            for (int mf = 0; mf < 4; ++mf)
                acc[mf][nf] = __builtin_amdgcn_mfma_f32_16x16x32_f16(
                    a[mf], b[nf], acc[mf][nf], 0, 0, 0);

        // ---- write-late: A(t+1) into buf^1 (its load has landed by now) ----
        if (t < 31) {
            f16x4 a4;
            a4[0] = (_Float16)avn.x; a4[1] = (_Float16)avn.y;
            a4[2] = (_Float16)avn.z; a4[3] = (_Float16)avn.w;
            *(f16x4*)&u.s.As[cur ^ 1][arow * 40 + akq] = a4;
        }
        __syncthreads();   // drains vmcnt (B t+1) + lgkmcnt (A t+1, reads t)
        cur ^= 1;
    }

    // ---- epilogue: dump logits to Ls[64][h*32+k] fp16 ----
    const int rb = g * 4;
#pragma unroll
    for (int nf = 0; nf < 4; ++nf) {
        const int nl = w * 64 + nf * 16 + col;
        if (nl < N_) {
            const int h = (nl * 8457) >> 18;       // nl/31 for nl<496
            const int slot = h * 32 + (nl - h * 31);
#pragma unroll
            for (int mf = 0; mf < 4; ++mf) {
                const int mr = mf * 16 + rb;
#pragma unroll
                for (int r = 0; r < 4; ++r)
                    u.Ls[(mr + r) * 512 + slot] = (_Float16)acc[mf][nf][r];
            }
        }
    }
    __syncthreads();

    // ---- softmax: 1024 (t,h) rows, 2 per thread; write WSM fp16 ----
#pragma unroll
    for (int p = 0; p < 2; ++p) {
        const int idx = tid + p * 512;
        const int mr = idx >> 4, h = idx & 15;
        const _Float16* lp = &u.Ls[mr * 512 + h * 32];
        float v[31];
#pragma unroll
        for (int c = 0; c < 4; ++c) {
            const f16x8 ch = *(const f16x8*)(lp + c * 8);
#pragma unroll
            for (int e = 0; e < 8; ++e) {
                const int k = c * 8 + e;
                if (k < 31) v[k] = (float)ch[e];
            }
        }
        float mx = v[0];
#pragma unroll
        for (int k = 1; k < 31; ++k) mx = fmaxf(mx, v[k]);
        float ssum = 0.f;
#pragma unroll
        for (int k = 0; k < 31; ++k) { v[k] = __expf(v[k] - mx); ssum += v[k]; }
        const float inv = 1.f / ssum;
        _Float16* op = WSM + (size_t)(m0 + mr) * 512 + h * 32;
#pragma unroll
        for (int c = 0; c < 4; ++c) {
            f16x8 ov;
#pragma unroll
            for (int e = 0; e < 8; ++e) {
                const int k = c * 8 + e;
                ov[e] = (k < 31) ? (_Float16)(v[k] * inv) : (_Float16)0.f;
            }
            *(f16x8*)(op + c * 8) = ov;
        }
    }
}

// ---------------------------------------------------------------------------
// K2: depthwise dynamic conv. Block = 64 t x one (b,h). xs[94][64] f32 with
// 16B-chunk XOR swizzle (row&7) for bank-free strided reads; ws[64][36] f32.
// Thread = (c-slot s, 4 consecutive t): shared-u loop -> each x b128 read
// feeds up to 16 fmas; w register-cached 4-wide.
// ---------------------------------------------------------------------------
__global__ __launch_bounds__(256)
void dconv(const float* __restrict__ X, const _Float16* __restrict__ WSM,
           float* __restrict__ out) {
    __shared__ float xs[94][64];
    __shared__ float ws[64][36];

    const int tid = threadIdx.x;
    const int t0 = blockIdx.x * 64;
    const int bh = (int)blockIdx.y;
    const int b = bh >> 4, h = bh & 15;

    // stage x window rows t0-15 .. t0+78 (swizzled 16B chunks)
    for (int task = tid; task < 94 * 16; task += 256) {
        const int r = task >> 4, sc = task & 15;
        const int tp = t0 + r - 15;
        f32x4 v = {};
        if (tp >= 0 && tp < T_)
            v = *(const f32x4*)(X + ((size_t)tp * B_ + b) * C_ + h * 64 + sc * 4);
        *(f32x4*)&xs[r][(sc ^ (r & 7)) * 4] = v;
    }
    // stage softmaxed weights (fp16 -> f32)
    {
        const int t = tid >> 2, kc = (tid & 3) * 8;
        const f16x8 wv =
            *(const f16x8*)(WSM + (size_t)((t0 + t) * B_ + b) * 512 + h * 32 + kc);
#pragma unroll
        for (int e = 0; e < 8; ++e) ws[t][kc + e] = (float)wv[e];
    }
    __syncthreads();

    const int s = tid & 15;
    const int tg4 = (tid >> 4) * 4;   // first of this thread's 4 t's
    f32x4 acc[4] = {};
    f32x4 wc[4];

#pragma unroll
    for (int rr = 0; rr < 34; ++rr) {
        const int r = tg4 + rr;
        const f32x4 xv = *(const f32x4*)&xs[r][(s ^ (r & 7)) * 4];
#pragma unroll
        for (int i = 0; i < 4; ++i) {
            const int k = rr - i;
            if (k < 0 || k > 30) continue;
            if ((k & 3) == 0) wc[i] = *(const f32x4*)&ws[tg4 + i][k];
            acc[i] += wc[i][k & 3] * xv;
        }
    }

#pragma unroll
    for (int i = 0; i < 4; ++i) {
        const int t = t0 + tg4 + i;
        *(f32x4*)(out + ((size_t)t * B_ + b) * C_ + h * 64 + s * 4) = acc[i];
    }
}

// ---------------------------------------------------------------------------
extern "C" void kernel_launch(void* const* d_in, const int* in_sizes, int n_in,
                              void* d_out, int out_size, void* d_ws,
                              size_t ws_size, hipStream_t stream) {
    const float* X = (const float*)d_in[0];
    const float* W = (const float*)d_in[1];
    float* out = (float*)d_out;

    _Float16* Wh = (_Float16*)d_ws;                              // 1 MiB
    _Float16* WSM = (_Float16*)((char*)d_ws + (size_t)NP * C_ * 2);  // 16 MiB

    cvt_w<<<256, 256, 0, stream>>>(W, Wh);
    gemm_softmax<<<256, 512, 0, stream>>>(X, Wh, WSM);
    dconv<<<dim3(T_ / 64, B_ * H_), 256, 0, stream>>>(X, WSM, out);
}

// Round 7
// 76.053 us; speedup vs baseline: 3.8594x; 1.1255x over previous
//
#include <hip/hip_runtime.h>
#include <cstddef>
#include <cstdint>

// Problem constants: T=2048, B=8, C=1024, H=16, K=31, P=15
constexpr int T_ = 2048;
constexpr int B_ = 8;
constexpr int C_ = 1024;
constexpr int H_ = 16;
constexpr int K_ = 31;
constexpr int P_ = 15;
constexpr int M_ = T_ * B_;   // 16384
constexpr int N_ = H_ * K_;   // 496
constexpr int NP = 512;       // padded N, slot layout n' = h*32 + k

typedef _Float16 f16x4 __attribute__((ext_vector_type(4)));
typedef _Float16 f16x8 __attribute__((ext_vector_type(8)));
typedef float f32x4 __attribute__((ext_vector_type(4)));

__device__ __forceinline__ void async_cp16(const void* g, void* l) {
    __builtin_amdgcn_global_load_lds(
        (const __attribute__((address_space(1))) void*)g,
        (__attribute__((address_space(3))) void*)l, 16, 0, 0);
}

// ---------------------------------------------------------------------------
// K0: fused convert. X (16384x1024 f32) -> Xh fp16; W (496x1024 f32) -> Wh
// (512x1024 fp16) in slot layout: row n' = h*32+k holds W row h*31+k, k<31;
// k==31 rows are zero. No baked permutation (K1 swizzles via its glds source).
// ---------------------------------------------------------------------------
constexpr int XCH = M_ * C_ / 8;    // 2,097,152 f16x8 chunks
constexpr int WCH = NP * C_ / 8;    // 65,536

__global__ __launch_bounds__(256)
void cvt_inputs(const float* __restrict__ X, const float* __restrict__ W,
                _Float16* __restrict__ Xh, _Float16* __restrict__ Wh) {
    const int id = blockIdx.x * 256 + threadIdx.x;
    if (id < XCH) {
        const float4 v0 = *(const float4*)(X + (size_t)id * 8);
        const float4 v1 = *(const float4*)(X + (size_t)id * 8 + 4);
        f16x8 hv;
        hv[0] = (_Float16)v0.x; hv[1] = (_Float16)v0.y;
        hv[2] = (_Float16)v0.z; hv[3] = (_Float16)v0.w;
        hv[4] = (_Float16)v1.x; hv[5] = (_Float16)v1.y;
        hv[6] = (_Float16)v1.z; hv[7] = (_Float16)v1.w;
        *(f16x8*)(Xh + (size_t)id * 8) = hv;
    } else {
        const int j = id - XCH;               // 0..WCH-1 (grid sized exactly)
        const int n = j >> 7, sp = j & 127;   // row, 8-half chunk
        const int h = n >> 5, k = n & 31;
        f16x8 hv = {};
        if (k < 31) {
            const float* wp = W + (size_t)(h * 31 + k) * C_ + sp * 8;
            const float4 v0 = *(const float4*)(wp);
            const float4 v1 = *(const float4*)(wp + 4);
            hv[0] = (_Float16)v0.x; hv[1] = (_Float16)v0.y;
            hv[2] = (_Float16)v0.z; hv[3] = (_Float16)v0.w;
            hv[4] = (_Float16)v1.x; hv[5] = (_Float16)v1.y;
            hv[6] = (_Float16)v1.z; hv[7] = (_Float16)v1.w;
        }
        *(f16x8*)(Wh + (size_t)n * C_ + sp * 8) = hv;
    }
}

// ---------------------------------------------------------------------------
// K1: m97-style GEMM + per-block softmax. BM=BN=128, BK=64, 256 thr
// (4 waves 2x2, each 64x64 = 4x4 frags x 2 k-substeps). Double-buffered;
// A and B both via global_load_lds w=16. Bank conflicts: LDS dest linear,
// global source chunk index XOR'd with (row&7); frag reads apply same XOR.
// Epilogue: logits -> LDS overlay (stride 136), softmax per (row, head),
// WSM fp16 out. Grid (128, 4) = 512 blocks = 2/CU.
// ---------------------------------------------------------------------------
__global__ __launch_bounds__(256)
void gemm_softmax(const _Float16* __restrict__ Xh,
                  const _Float16* __restrict__ Wh,
                  _Float16* __restrict__ WSM) {
    __shared__ union {
        struct { _Float16 A[2][128 * 64]; _Float16 B[2][128 * 64]; } s;
        _Float16 Ls[128 * 136];   // logits overlay (phase-disjoint), 34 KB
    } u;

    const int tid = threadIdx.x;
    const int lane = tid & 63;
    const int w = tid >> 6;
    const int wm = (w >> 1) * 64;
    const int wn = (w & 1) * 64;
    const int col = lane & 15;
    const int g = lane >> 4;
    const int m0 = blockIdx.x * 128;
    const int n0 = blockIdx.y * 128;

    // staging: 4 A-chunks + 4 B-chunks per thread per k-step.
    // chunk ci = p*256+tid -> LDS halves [ci*8, ci*8+8); row r = ci>>3,
    // store-pos cs = ci&7; global source holds logical chunk cs^(r&7).
    const _Float16* asrc[4];
    const _Float16* bsrc[4];
#pragma unroll
    for (int p = 0; p < 4; ++p) {
        const int ci = p * 256 + tid;
        const int r = ci >> 3, cs = ci & 7;
        const int cl = cs ^ (r & 7);
        asrc[p] = Xh + (size_t)(m0 + r) * C_ + cl * 8;
        bsrc[p] = Wh + (size_t)(n0 + r) * C_ + cl * 8;
    }

    f32x4 acc[4][4] = {};

    // prologue: stage k-step 0 into buffer 0
#pragma unroll
    for (int p = 0; p < 4; ++p) {
        const int ci = p * 256 + tid;
        async_cp16(asrc[p], &u.s.A[0][ci * 8]);
        async_cp16(bsrc[p], &u.s.B[0][ci * 8]);
    }
    __syncthreads();

    int cur = 0;
    for (int t = 0; t < 16; ++t) {
        if (t < 15) {
            const int k1 = (t + 1) * 64;
#pragma unroll
            for (int p = 0; p < 4; ++p) {
                const int ci = p * 256 + tid;
                async_cp16(asrc[p] + k1, &u.s.A[cur ^ 1][ci * 8]);
                async_cp16(bsrc[p] + k1, &u.s.B[cur ^ 1][ci * 8]);
            }
        }

        // fragments (swizzled reads) + 32 MFMA
        f16x8 a[2][4], b[2][4];
#pragma unroll
        for (int kk = 0; kk < 2; ++kk) {
#pragma unroll
            for (int mf = 0; mf < 4; ++mf) {
                const int row = wm + mf * 16 + col;
                const int c = ((kk << 2) | g) ^ (row & 7);
                a[kk][mf] = *(const f16x8*)&u.s.A[cur][row * 64 + c * 8];
            }
#pragma unroll
            for (int nf = 0; nf < 4; ++nf) {
                const int row = wn + nf * 16 + col;
                const int c = ((kk << 2) | g) ^ (row & 7);
                b[kk][nf] = *(const f16x8*)&u.s.B[cur][row * 64 + c * 8];
            }
        }
#pragma unroll
        for (int kk = 0; kk < 2; ++kk)
#pragma unroll
            for (int nf = 0; nf < 4; ++nf)
#pragma unroll
                for (int mf = 0; mf < 4; ++mf)
                    acc[mf][nf] = __builtin_amdgcn_mfma_f32_16x16x32_f16(
                        a[kk][mf], b[kk][nf], acc[mf][nf], 0, 0, 0);
        __syncthreads();
        cur ^= 1;
    }

    // ---- dump logits to overlay: Ls[row][nl], stride 136 ----
    const int rb = g * 4;
#pragma unroll
    for (int nf = 0; nf < 4; ++nf) {
        const int nl = wn + nf * 16 + col;
#pragma unroll
        for (int mf = 0; mf < 4; ++mf) {
            const int row = wm + mf * 16 + rb;
#pragma unroll
            for (int r = 0; r < 4; ++r)
                u.Ls[(row + r) * 136 + nl] = (_Float16)acc[mf][nf][r];
        }
    }
    __syncthreads();

    // ---- softmax: 512 (row, head-local) tasks, 2 per thread ----
#pragma unroll
    for (int p = 0; p < 2; ++p) {
        const int task = tid + p * 256;
        const int row = task >> 2, hl = task & 3;
        const _Float16* lp = &u.Ls[row * 136 + hl * 32];
        float v[32];
#pragma unroll
        for (int c = 0; c < 4; ++c) {
            const f16x8 ch = *(const f16x8*)(lp + c * 8);
#pragma unroll
            for (int e = 0; e < 8; ++e) v[c * 8 + e] = (float)ch[e];
        }
        float mx = v[0];
#pragma unroll
        for (int k = 1; k < 31; ++k) mx = fmaxf(mx, v[k]);
        float ssum = 0.f;
#pragma unroll
        for (int k = 0; k < 31; ++k) { v[k] = __expf(v[k] - mx); ssum += v[k]; }
        const float inv = 1.f / ssum;
        _Float16* op = WSM + (size_t)(m0 + row) * NP + n0 + hl * 32;
#pragma unroll
        for (int c = 0; c < 4; ++c) {
            f16x8 ov;
#pragma unroll
            for (int e = 0; e < 8; ++e) {
                const int k = c * 8 + e;
                ov[e] = (k < 31) ? (_Float16)(v[k] * inv) : (_Float16)0.f;
            }
            *(f16x8*)(op + c * 8) = ov;
        }
    }
}

// ---------------------------------------------------------------------------
// K2: depthwise dynamic conv, x read as fp16 (Xh). Block = 64 t x one (b,h).
// xs[94][64] f32, 16B-chunk XOR swizzle (row&7); ws[64][36] f32.
// Conv loop identical to round 6 (verified).
// ---------------------------------------------------------------------------
__global__ __launch_bounds__(256)
void dconv(const _Float16* __restrict__ Xh, const _Float16* __restrict__ WSM,
           float* __restrict__ out) {
    __shared__ float xs[94][64];
    __shared__ float ws[64][36];

    const int tid = threadIdx.x;
    const int t0 = blockIdx.x * 64;
    const int bh = (int)blockIdx.y;
    const int b = bh >> 4, h = bh & 15;

    // stage x window rows t0-15 .. t0+78: f16x8 loads -> 2 swizzled f32x4
    for (int task = tid; task < 94 * 8; task += 256) {
        const int r = task >> 3, hc = task & 7;
        const int tp = t0 + r - 15;
        f16x8 v = {};
        if (tp >= 0 && tp < T_)
            v = *(const f16x8*)(Xh + ((size_t)tp * B_ + b) * C_ + h * 64 + hc * 8);
        f32x4 lo, hi;
        lo[0] = (float)v[0]; lo[1] = (float)v[1];
        lo[2] = (float)v[2]; lo[3] = (float)v[3];
        hi[0] = (float)v[4]; hi[1] = (float)v[5];
        hi[2] = (float)v[6]; hi[3] = (float)v[7];
        const int c0 = (2 * hc) ^ (r & 7), c1 = (2 * hc + 1) ^ (r & 7);
        *(f32x4*)&xs[r][c0 * 4] = lo;
        *(f32x4*)&xs[r][c1 * 4] = hi;
    }
    // stage softmaxed weights (fp16 -> f32)
    {
        const int t = tid >> 2, kc = (tid & 3) * 8;
        const f16x8 wv =
            *(const f16x8*)(WSM + ((size_t)(t0 + t) * B_ + b) * NP + h * 32 + kc);
#pragma unroll
        for (int e = 0; e < 8; ++e) ws[t][kc + e] = (float)wv[e];
    }
    __syncthreads();

    const int s = tid & 15;
    const int tg4 = (tid >> 4) * 4;
    f32x4 acc[4] = {};
    f32x4 wc[4];

#pragma unroll
    for (int rr = 0; rr < 34; ++rr) {
        const int r = tg4 + rr;
        const f32x4 xv = *(const f32x4*)&xs[r][(s ^ (r & 7)) * 4];
#pragma unroll
        for (int i = 0; i < 4; ++i) {
            const int k = rr - i;
            if (k < 0 || k > 30) continue;
            if ((k & 3) == 0) wc[i] = *(const f32x4*)&ws[tg4 + i][k];
            acc[i] += wc[i][k & 3] * xv;
        }
    }

#pragma unroll
    for (int i = 0; i < 4; ++i) {
        const int t = t0 + tg4 + i;
        *(f32x4*)(out + ((size_t)t * B_ + b) * C_ + h * 64 + s * 4) = acc[i];
    }
}

// ---------------------------------------------------------------------------
extern "C" void kernel_launch(void* const* d_in, const int* in_sizes, int n_in,
                              void* d_out, int out_size, void* d_ws,
                              size_t ws_size, hipStream_t stream) {
    const float* X = (const float*)d_in[0];
    const float* W = (const float*)d_in[1];
    float* out = (float*)d_out;

    // workspace: Wh (1 MiB) | WSM (16 MiB) | Xh (32 MiB)  = 49 MiB
    _Float16* Wh = (_Float16*)d_ws;
    _Float16* WSM = (_Float16*)((char*)d_ws + (size_t)NP * C_ * 2);
    _Float16* Xh = (_Float16*)((char*)d_ws + (size_t)NP * C_ * 2 +
                               (size_t)M_ * NP * 2);

    cvt_inputs<<<(XCH + WCH) / 256, 256, 0, stream>>>(X, W, Xh, Wh);
    gemm_softmax<<<dim3(M_ / 128, NP / 128), 256, 0, stream>>>(Xh, Wh, WSM);
    dconv<<<dim3(T_ / 64, B_ * H_), 256, 0, stream>>>(Xh, WSM, out);
}

// Round 8
// 73.695 us; speedup vs baseline: 3.9829x; 1.0320x over previous
//
#include <hip/hip_runtime.h>
#include <cstddef>
#include <cstdint>

// Problem constants: T=2048, B=8, C=1024, H=16, K=31, P=15
constexpr int T_ = 2048;
constexpr int B_ = 8;
constexpr int C_ = 1024;
constexpr int H_ = 16;
constexpr int K_ = 31;
constexpr int P_ = 15;
constexpr int M_ = T_ * B_;   // 16384
constexpr int N_ = H_ * K_;   // 496
constexpr int NP = 512;       // padded N, slot layout n' = h*32 + k

typedef _Float16 f16x4 __attribute__((ext_vector_type(4)));
typedef _Float16 f16x8 __attribute__((ext_vector_type(8)));
typedef float f32x4 __attribute__((ext_vector_type(4)));

__device__ __forceinline__ void async_cp16(const void* g, void* l) {
    __builtin_amdgcn_global_load_lds(
        (const __attribute__((address_space(1))) void*)g,
        (__attribute__((address_space(3))) void*)l, 16, 0, 0);
}

// ---------------------------------------------------------------------------
// K0: fused convert. X -> Xh fp16; W -> Wh (512x1024 fp16, slot layout
// n' = h*32+k; k==31 rows zero).
// ---------------------------------------------------------------------------
constexpr int XCH = M_ * C_ / 8;    // 2,097,152 f16x8 chunks
constexpr int WCH = NP * C_ / 8;    // 65,536

__global__ __launch_bounds__(256)
void cvt_inputs(const float* __restrict__ X, const float* __restrict__ W,
                _Float16* __restrict__ Xh, _Float16* __restrict__ Wh) {
    const int id = blockIdx.x * 256 + threadIdx.x;
    if (id < XCH) {
        const float4 v0 = *(const float4*)(X + (size_t)id * 8);
        const float4 v1 = *(const float4*)(X + (size_t)id * 8 + 4);
        f16x8 hv;
        hv[0] = (_Float16)v0.x; hv[1] = (_Float16)v0.y;
        hv[2] = (_Float16)v0.z; hv[3] = (_Float16)v0.w;
        hv[4] = (_Float16)v1.x; hv[5] = (_Float16)v1.y;
        hv[6] = (_Float16)v1.z; hv[7] = (_Float16)v1.w;
        *(f16x8*)(Xh + (size_t)id * 8) = hv;
    } else {
        const int j = id - XCH;
        const int n = j >> 7, sp = j & 127;
        const int h = n >> 5, k = n & 31;
        f16x8 hv = {};
        if (k < 31) {
            const float* wp = W + (size_t)(h * 31 + k) * C_ + sp * 8;
            const float4 v0 = *(const float4*)(wp);
            const float4 v1 = *(const float4*)(wp + 4);
            hv[0] = (_Float16)v0.x; hv[1] = (_Float16)v0.y;
            hv[2] = (_Float16)v0.z; hv[3] = (_Float16)v0.w;
            hv[4] = (_Float16)v1.x; hv[5] = (_Float16)v1.y;
            hv[6] = (_Float16)v1.z; hv[7] = (_Float16)v1.w;
        }
        *(f16x8*)(Wh + (size_t)n * C_ + sp * 8) = hv;
    }
}

// ---------------------------------------------------------------------------
// K1: GEMM + per-block softmax, counted-vmcnt pipeline (T4).
// BM=BN=128, BK=64, 256 thr (4 waves 2x2, wave tile 64x64).
// A: 3-deep buffers (prefetch distance 2, covers L3 latency).
// B: 2-deep buffers (Wh is 1MB, L2-resident, short latency).
// Per iter: issue B(t+1), A(t+2); compute(t); s_waitcnt vmcnt(4); s_barrier.
// vmcnt(4) leaves only A(t+2) in flight -> loads span barriers (never 0).
// LDS 80 KB -> 2 blocks/CU. Bank conflicts: linear glds dest + XOR'd global
// source chunk; frag reads apply the same XOR (both-sides rule).
// ---------------------------------------------------------------------------
__global__ __launch_bounds__(256)
void gemm_softmax(const _Float16* __restrict__ Xh,
                  const _Float16* __restrict__ Wh,
                  _Float16* __restrict__ WSM) {
    __shared__ union {
        struct { _Float16 A[3][128 * 64]; _Float16 B[2][128 * 64]; } s;
        _Float16 Ls[128 * 136];   // logits overlay (phase-disjoint), 34 KB
    } u;

    const int tid = threadIdx.x;
    const int lane = tid & 63;
    const int w = tid >> 6;
    const int wm = (w >> 1) * 64;
    const int wn = (w & 1) * 64;
    const int col = lane & 15;
    const int g = lane >> 4;
    const int m0 = blockIdx.x * 128;
    const int n0 = blockIdx.y * 128;

    // staging: 4 A-chunks + 4 B-chunks per thread per k-step.
    // chunk ci = p*256+tid -> LDS halves [ci*8, ci*8+8); row r = ci>>3,
    // store-pos cs = ci&7; global source holds logical chunk cs^(r&7).
    const _Float16* asrc[4];
    const _Float16* bsrc[4];
#pragma unroll
    for (int p = 0; p < 4; ++p) {
        const int ci = p * 256 + tid;
        const int r = ci >> 3, cs = ci & 7;
        const int cl = cs ^ (r & 7);
        asrc[p] = Xh + (size_t)(m0 + r) * C_ + cl * 8;
        bsrc[p] = Wh + (size_t)(n0 + r) * C_ + cl * 8;
    }

    f32x4 acc[4][4] = {};

    // ---- prologue: A(0), B(0), A(1); wait all but A(1) ----
#pragma unroll
    for (int p = 0; p < 4; ++p) {
        const int ci = p * 256 + tid;
        async_cp16(asrc[p], &u.s.A[0][ci * 8]);
    }
#pragma unroll
    for (int p = 0; p < 4; ++p) {
        const int ci = p * 256 + tid;
        async_cp16(bsrc[p], &u.s.B[0][ci * 8]);
    }
#pragma unroll
    for (int p = 0; p < 4; ++p) {
        const int ci = p * 256 + tid;
        async_cp16(asrc[p] + 64, &u.s.A[1][ci * 8]);
    }
    asm volatile("s_waitcnt vmcnt(4)" ::: "memory");
    __builtin_amdgcn_s_barrier();
    __builtin_amdgcn_sched_barrier(0);

    for (int t = 0; t < 16; ++t) {
        const int ca = t % 3, cb = t & 1;
        // ---- issue B(t+1) then A(t+2) (issue order matters for vmcnt) ----
        if (t < 15) {
            const int k1 = (t + 1) * 64;
#pragma unroll
            for (int p = 0; p < 4; ++p) {
                const int ci = p * 256 + tid;
                async_cp16(bsrc[p] + k1, &u.s.B[cb ^ 1][ci * 8]);
            }
        }
        if (t < 14) {
            const int k2 = (t + 2) * 64;
            const int ca2 = (t + 2) % 3;
#pragma unroll
            for (int p = 0; p < 4; ++p) {
                const int ci = p * 256 + tid;
                async_cp16(asrc[p] + k2, &u.s.A[ca2][ci * 8]);
            }
        }

        // ---- compute k-step t ----
        f16x8 a[2][4], b[2][4];
#pragma unroll
        for (int kk = 0; kk < 2; ++kk) {
#pragma unroll
            for (int mf = 0; mf < 4; ++mf) {
                const int row = wm + mf * 16 + col;
                const int c = ((kk << 2) | g) ^ (row & 7);
                a[kk][mf] = *(const f16x8*)&u.s.A[ca][row * 64 + c * 8];
            }
#pragma unroll
            for (int nf = 0; nf < 4; ++nf) {
                const int row = wn + nf * 16 + col;
                const int c = ((kk << 2) | g) ^ (row & 7);
                b[kk][nf] = *(const f16x8*)&u.s.B[cb][row * 64 + c * 8];
            }
        }
#pragma unroll
        for (int kk = 0; kk < 2; ++kk)
#pragma unroll
            for (int nf = 0; nf < 4; ++nf)
#pragma unroll
                for (int mf = 0; mf < 4; ++mf)
                    acc[mf][nf] = __builtin_amdgcn_mfma_f32_16x16x32_f16(
                        a[kk][mf], b[kk][nf], acc[mf][nf], 0, 0, 0);

        // ---- counted wait: A(t+1), B(t+1) done; A(t+2) stays in flight ----
        if (t < 14) {
            asm volatile("s_waitcnt vmcnt(4)" ::: "memory");
        } else {
            asm volatile("s_waitcnt vmcnt(0)" ::: "memory");
        }
        __builtin_amdgcn_s_barrier();
        __builtin_amdgcn_sched_barrier(0);
    }

    // ---- dump logits to overlay: Ls[row][nl], stride 136 ----
    const int rb = g * 4;
#pragma unroll
    for (int nf = 0; nf < 4; ++nf) {
        const int nl = wn + nf * 16 + col;
#pragma unroll
        for (int mf = 0; mf < 4; ++mf) {
            const int row = wm + mf * 16 + rb;
#pragma unroll
            for (int r = 0; r < 4; ++r)
                u.Ls[(row + r) * 136 + nl] = (_Float16)acc[mf][nf][r];
        }
    }
    __syncthreads();

    // ---- softmax: 512 (row, head-local) tasks, 2 per thread ----
#pragma unroll
    for (int p = 0; p < 2; ++p) {
        const int task = tid + p * 256;
        const int row = task >> 2, hl = task & 3;
        const _Float16* lp = &u.Ls[row * 136 + hl * 32];
        float v[32];
#pragma unroll
        for (int c = 0; c < 4; ++c) {
            const f16x8 ch = *(const f16x8*)(lp + c * 8);
#pragma unroll
            for (int e = 0; e < 8; ++e) v[c * 8 + e] = (float)ch[e];
        }
        float mx = v[0];
#pragma unroll
        for (int k = 1; k < 31; ++k) mx = fmaxf(mx, v[k]);
        float ssum = 0.f;
#pragma unroll
        for (int k = 0; k < 31; ++k) { v[k] = __expf(v[k] - mx); ssum += v[k]; }
        const float inv = 1.f / ssum;
        _Float16* op = WSM + (size_t)(m0 + row) * NP + n0 + hl * 32;
#pragma unroll
        for (int c = 0; c < 4; ++c) {
            f16x8 ov;
#pragma unroll
            for (int e = 0; e < 8; ++e) {
                const int k = c * 8 + e;
                ov[e] = (k < 31) ? (_Float16)(v[k] * inv) : (_Float16)0.f;
            }
            *(f16x8*)(op + c * 8) = ov;
        }
    }
}

// ---------------------------------------------------------------------------
// K2: depthwise dynamic conv, x read as fp16 (Xh). Block = 64 t x one (b,h).
// xs[94][64] f32, 16B-chunk XOR swizzle (row&7); ws[64][36] f32 (vector
// stores, rows are 16B-aligned since 36*4=144=9*16).
// ---------------------------------------------------------------------------
__global__ __launch_bounds__(256)
void dconv(const _Float16* __restrict__ Xh, const _Float16* __restrict__ WSM,
           float* __restrict__ out) {
    __shared__ float xs[94][64];
    __shared__ float ws[64][36];

    const int tid = threadIdx.x;
    const int t0 = blockIdx.x * 64;
    const int bh = (int)blockIdx.y;
    const int b = bh >> 4, h = bh & 15;

    // stage x window rows t0-15 .. t0+78: f16x8 loads -> 2 swizzled f32x4
    for (int task = tid; task < 94 * 8; task += 256) {
        const int r = task >> 3, hc = task & 7;
        const int tp = t0 + r - 15;
        f16x8 v = {};
        if (tp >= 0 && tp < T_)
            v = *(const f16x8*)(Xh + ((size_t)tp * B_ + b) * C_ + h * 64 + hc * 8);
        f32x4 lo, hi;
        lo[0] = (float)v[0]; lo[1] = (float)v[1];
        lo[2] = (float)v[2]; lo[3] = (float)v[3];
        hi[0] = (float)v[4]; hi[1] = (float)v[5];
        hi[2] = (float)v[6]; hi[3] = (float)v[7];
        const int c0 = (2 * hc) ^ (r & 7), c1 = (2 * hc + 1) ^ (r & 7);
        *(f32x4*)&xs[r][c0 * 4] = lo;
        *(f32x4*)&xs[r][c1 * 4] = hi;
    }
    // stage softmaxed weights (fp16 -> f32), vectorized
    {
        const int t = tid >> 2, kc = (tid & 3) * 8;
        const f16x8 wv =
            *(const f16x8*)(WSM + ((size_t)(t0 + t) * B_ + b) * NP + h * 32 + kc);
        f32x4 lo, hi;
        lo[0] = (float)wv[0]; lo[1] = (float)wv[1];
        lo[2] = (float)wv[2]; lo[3] = (float)wv[3];
        hi[0] = (float)wv[4]; hi[1] = (float)wv[5];
        hi[2] = (float)wv[6]; hi[3] = (float)wv[7];
        *(f32x4*)&ws[t][kc] = lo;
        *(f32x4*)&ws[t][kc + 4] = hi;
    }
    __syncthreads();

    const int s = tid & 15;
    const int tg4 = (tid >> 4) * 4;
    f32x4 acc[4] = {};
    f32x4 wc[4];

#pragma unroll
    for (int rr = 0; rr < 34; ++rr) {
        const int r = tg4 + rr;
        const f32x4 xv = *(const f32x4*)&xs[r][(s ^ (r & 7)) * 4];
#pragma unroll
        for (int i = 0; i < 4; ++i) {
            const int k = rr - i;
            if (k < 0 || k > 30) continue;
            if ((k & 3) == 0) wc[i] = *(const f32x4*)&ws[tg4 + i][k];
            acc[i] += wc[i][k & 3] * xv;
        }
    }

#pragma unroll
    for (int i = 0; i < 4; ++i) {
        const int t = t0 + tg4 + i;
        *(f32x4*)(out + ((size_t)t * B_ + b) * C_ + h * 64 + s * 4) = acc[i];
    }
}

// ---------------------------------------------------------------------------
extern "C" void kernel_launch(void* const* d_in, const int* in_sizes, int n_in,
                              void* d_out, int out_size, void* d_ws,
                              size_t ws_size, hipStream_t stream) {
    const float* X = (const float*)d_in[0];
    const float* W = (const float*)d_in[1];
    float* out = (float*)d_out;

    // workspace: Wh (1 MiB) | WSM (16 MiB) | Xh (32 MiB)  = 49 MiB
    _Float16* Wh = (_Float16*)d_ws;
    _Float16* WSM = (_Float16*)((char*)d_ws + (size_t)NP * C_ * 2);
    _Float16* Xh = (_Float16*)((char*)d_ws + (size_t)NP * C_ * 2 +
                               (size_t)M_ * NP * 2);

    cvt_inputs<<<(XCH + WCH) / 256, 256, 0, stream>>>(X, W, Xh, Wh);
    gemm_softmax<<<dim3(M_ / 128, NP / 128), 256, 0, stream>>>(Xh, Wh, WSM);
    dconv<<<dim3(T_ / 64, B_ * H_), 256, 0, stream>>>(Xh, WSM, out);
}